// Round 12
// baseline (115.999 us; speedup 1.0000x reference)
//
#include <hip/hip_runtime.h>

typedef __attribute__((ext_vector_type(2))) float  f32x2;
typedef __attribute__((ext_vector_type(4))) float  f32x4;
typedef __attribute__((ext_vector_type(4))) unsigned int u32x4;
typedef _Float16 f16;
typedef __attribute__((ext_vector_type(2))) _Float16 f16x2;
typedef __attribute__((ext_vector_type(4))) _Float16 f16x4;
typedef __attribute__((ext_vector_type(8))) _Float16 f16x8;

#define S_LEN 2048
#define E_DIM 512
#define NH 64
#define DK 8

// ---------------------------------------------------------------------------
// Kernel 1: MFMA attention — EXACT R14 (best measured; attn+gap = 17.3us via
// R17 probe). Untouched this round.
// ---------------------------------------------------------------------------
__global__ __launch_bounds__(256) void attn_stage(
    const float* __restrict__ X,    // (8,2048,512) fp32
    const float* __restrict__ TH,   // (8,) fp32
    const float* __restrict__ W,    // (512,512) fp32
    f16* __restrict__ Wb,           // ws: 512x512 f16
    f16* __restrict__ A)            // ws: 16384 x 512 fp16
{
    __shared__ __align__(16) f16 Ps[4][NH][DK];   // 4 KB
    __shared__ __align__(16) f16 Pt[4][16][72];   // 9 KB
    __shared__ __align__(16) f16 Ev[4][NH * NH];  // 32 KB
    const int tid  = threadIdx.x;
    const int wv   = tid >> 6;
    const int lane = tid & 63;
    const int q    = lane >> 4;
    const int l    = lane & 15;
    const int t    = blockIdx.x * 4 + wv;    // token id

    // Side job: W fp32 -> f16 (65536 float4s == 256 blocks x 256 threads)
    if (blockIdx.x < 256) {
        const int i = blockIdx.x * 256 + tid;
        const float4 v = *(const float4*)(W + (size_t)i * 4);
        f16x4 o = {(f16)v.x, (f16)v.y, (f16)v.z, (f16)v.w};
        *(f16x4*)(Wb + (size_t)i * 4) = o;
    }

    const float4 t0 = *(const float4*)(TH);
    const float4 t1 = *(const float4*)(TH + 4);
    const float4 x0 = *(const float4*)(X + (size_t)t * E_DIM + lane * DK);
    const float4 x1 = *(const float4*)(X + (size_t)t * E_DIM + lane * DK + 4);

    float p[DK];
    p[0] = __cosf(x0.x + t0.x); p[1] = __cosf(x0.y + t0.y);
    p[2] = __cosf(x0.z + t0.z); p[3] = __cosf(x0.w + t0.w);
    p[4] = __cosf(x1.x + t1.x); p[5] = __cosf(x1.y + t1.y);
    p[6] = __cosf(x1.z + t1.z); p[7] = __cosf(x1.w + t1.w);

    // Ps[h][d] = p*cs  (cs^2 = (1/sqrt(8))*log2(e))
    const float cs = 0.714227053f;
    f16x8 psv;
    #pragma unroll
    for (int d = 0; d < DK; ++d) psv[d] = (f16)(p[d] * cs);
    *(f16x8*)&Ps[wv][lane][0] = psv;
    #pragma unroll
    for (int d = 0; d < DK; ++d) Pt[wv][d][lane] = (f16)p[d];
    __syncthreads();

    const f16x8 z8  = {(f16)0,(f16)0,(f16)0,(f16)0,(f16)0,(f16)0,(f16)0,(f16)0};
    const f16x8 one8= {(f16)1,(f16)1,(f16)1,(f16)1,(f16)1,(f16)1,(f16)1,(f16)1};

    f16x8 f[4];
    #pragma unroll
    for (int i = 0; i < 4; ++i) {
        const f16x8 v = *(const f16x8*)&Ps[wv][i*16 + l][0];
        f[i] = (q == 0) ? v : z8;
    }
    f32x4 St[4][4];
    #pragma unroll
    for (int i = 0; i < 4; ++i)
        #pragma unroll
        for (int jb = 0; jb < 4; ++jb) {
            f32x4 zc = {0.f, 0.f, 0.f, 0.f};
            St[i][jb] = __builtin_amdgcn_mfma_f32_16x16x32_f16(f[i], f[jb], zc, 0, 0, 0);
        }

    // E = exp2(S2), row-major via symmetry; chunk-8 XOR swizzle on cols.
    #pragma unroll
    for (int i = 0; i < 4; ++i)
        #pragma unroll
        for (int jb = 0; jb < 4; ++jb) {
            const float e0 = __builtin_amdgcn_exp2f(St[i][jb][0]);
            const float e1 = __builtin_amdgcn_exp2f(St[i][jb][1]);
            const float e2 = __builtin_amdgcn_exp2f(St[i][jb][2]);
            const float e3 = __builtin_amdgcn_exp2f(St[i][jb][3]);
            f16x4 w4;
            w4[0] = (f16)e0; w4[1] = (f16)e1; w4[2] = (f16)e2; w4[3] = (f16)e3;
            const int row = jb * 16 + l;
            const int c8  = (i * 2 + (q >> 1)) ^ (l & 7);
            const int col = c8 * 8 + (q & 1) * 4;
            *(f16x4*)&Ev[wv][row * 64 + col] = w4;
        }
    __syncthreads();

    // D2 = [Pᵀ; ones; 0]·Eᵀ over K=64.
    f32x4 d2[4] = {};
    #pragma unroll
    for (int kh = 0; kh < 2; ++kh) {
        const f16x8 av  = *(const f16x8*)&Pt[wv][l][kh * 32 + q * 8];
        const f16x8 a2f = (l < 8) ? av : ((l == 8) ? one8 : z8);
        #pragma unroll
        for (int nb = 0; nb < 4; ++nb) {
            const int c8 = (kh * 4 + q) ^ (l & 7);
            const f16x8 bv = *(const f16x8*)&Ev[wv][(nb * 16 + l) * 64 + c8 * 8];
            d2[nb] = __builtin_amdgcn_mfma_f32_16x16x32_f16(a2f, bv, d2[nb], 0, 0, 0);
        }
    }

    float rsinv[4];
    #pragma unroll
    for (int nb = 0; nb < 4; ++nb) {
        const int rs = __builtin_amdgcn_ds_bpermute((32 + l) * 4,
                           __float_as_int(d2[nb][0]));
        rsinv[nb] = __builtin_amdgcn_rcpf(__int_as_float(rs));
    }

    if (lane < 32) {
        const int s   = t & (S_LEN - 1);
        const int cb  = (t & 63) * DK + q * 4;
        const int rb  = ((t >> 11) << 11) + (s >> 6);
        #pragma unroll
        for (int nb = 0; nb < 4; ++nb) {
            const int h   = nb * 16 + l;
            const int row = rb + h * 32;
            f16x4 o;
            #pragma unroll
            for (int r = 0; r < 4; ++r) o[r] = (f16)(d2[nb][r] * rsinv[nb]);
            *(f16x4*)(A + (size_t)row * E_DIM + cb) = o;   // normal store (L2-merged)
        }
    }
}

// ---------------------------------------------------------------------------
// Kernel 2 (R19): OUT = A @ W^T + bias — BARRIER-FREE K-LOOP.
// A tile (64x512 f16 = 64KB) staged in LDS ONCE (XOR-swizzled chunks, 2-way
// bank aliasing only = free). W (L2-resident f16) read per-lane directly from
// global as B-fragments — no W staging, no per-iteration barriers; compiler
// free to pipeline the 4 B-loads/iter across the 16 k-iters. Each of the 4
// waves owns a distinct 64-col slice (no duplicate W reads: 128MB L2 total,
// same as R18). acc[4][4] = 64 VGPR (same footprint as R18's acc[2][8]).
// Barriers in entire kernel: 2 (post-A-stage, pre-epilogue LDS reuse).
// Epilogue: per-wave private ldsT region (aliases dead ldsA), intra-wave
// LDS ordering is hardware-guaranteed (DS ops in order per wave).
// ---------------------------------------------------------------------------
#define GBM 64
#define GBN 256

__global__ __launch_bounds__(256) void gemm_bias(
    const f16* __restrict__ A,        // 16384 x 512 f16 (ws)
    const f16* __restrict__ W,        // 512 x 512 f16 (ws)
    const float* __restrict__ BIAS,   // 512 fp32
    float* __restrict__ OUT)          // 16384 x 512 fp32
{
    // 64KB: K-loop = staged A (64 rows x 512 f16, swizzled);
    // epilogue = 4 per-wave ldsT regions (16 x 68 f32 each), aliased.
    __shared__ __align__(16) char ldsraw[GBM * 512 * 2];
    f16* ldsA = (f16*)ldsraw;
    const int tid  = threadIdx.x;
    const int lane = tid & 63;
    const int wave = tid >> 6;               // 0..3
    const int quad = lane >> 4;              // 0..3 (k-chunk)
    const int l16  = lane & 15;              // fragment row/col
    const int cg   = blockIdx.x >> 8;        // col-group 0..1
    const int mg   = blockIdx.x & 255;       // m-group 0..255
    const int m0   = mg * GBM;
    const int colbase = cg * GBN + wave * 64;   // wave's OUT-col / W-row base

    // ---- stage A once: 4096 16B-chunks, XOR-swizzle chunk index by row ----
    u32x4 st[16];
    #pragma unroll
    for (int i = 0; i < 16; ++i) {
        const int cid = tid + i * 256;       // 0..4095
        const int r = cid >> 6, c = cid & 63;
        st[i] = *(const u32x4*)(A + (size_t)(m0 + r) * 512 + c * 8);
    }
    #pragma unroll
    for (int i = 0; i < 16; ++i) {
        const int cid = tid + i * 256;
        const int r = cid >> 6, c = cid & 63;
        *(u32x4*)(ldsA + r * 512 + ((c ^ (r & 7)) * 8)) = st[i];
    }
    __syncthreads();                         // A visible to all waves

    // ---- barrier-free K-loop: 16 iters x {4 global B-loads, 4 ds A-reads,
    //      16 MFMA} ----
    f32x4 acc[4][4] = {};
    #pragma unroll 4
    for (int kt = 0; kt < 16; ++kt) {
        const int kb = kt * 32;
        f16x8 bfr[4];
        #pragma unroll
        for (int ni = 0; ni < 4; ++ni)
            bfr[ni] = *(const f16x8*)(W + (size_t)(colbase + ni * 16 + l16) * 512
                                        + kb + quad * 8);
        #pragma unroll
        for (int mi = 0; mi < 4; ++mi) {
            const int ra = mi * 16 + l16;
            const int cc = ((kb >> 3) + quad) ^ (ra & 7);
            const f16x8 afr = *(const f16x8*)(ldsA + ra * 512 + cc * 8);
            #pragma unroll
            for (int ni = 0; ni < 4; ++ni)
                acc[mi][ni] = __builtin_amdgcn_mfma_f32_16x16x32_f16(
                    afr, bfr[ni], acc[mi][ni], 0, 0, 0);
        }
    }
    __syncthreads();                         // ldsA dead; safe to alias as ldsT

    // ---- epilogue: per-wave transpose + bias + nt store ----
    float* ldsT = (float*)ldsraw + wave * (16 * 68);
    float4 bias4 = *(const float4*)(BIAS + colbase + l16 * 4);
    #pragma unroll
    for (int mi = 0; mi < 4; ++mi) {
        #pragma unroll
        for (int ni = 0; ni < 4; ++ni)
            #pragma unroll
            for (int r = 0; r < 4; ++r)
                ldsT[(quad * 4 + r) * 68 + ni * 16 + l16] = acc[mi][ni][r];
        // intra-wave ds_write->ds_read ordering is in-order per wave
        #pragma unroll
        for (int j = 0; j < 4; ++j) {
            const int row = j * 4 + quad;            // 0..15
            f32x4 v = *(const f32x4*)&ldsT[row * 68 + l16 * 4];
            v.x += bias4.x; v.y += bias4.y; v.z += bias4.z; v.w += bias4.w;
            float* o = OUT + (size_t)(m0 + mi * 16 + row) * 512
                           + colbase + l16 * 4;
            __builtin_nontemporal_store(v, (f32x4*)o);
        }
    }
}

extern "C" void kernel_launch(void* const* d_in, const int* in_sizes, int n_in,
                              void* d_out, int out_size, void* d_ws, size_t ws_size,
                              hipStream_t stream) {
    const float* X  = (const float*)d_in[0];   // x fp32
    const float* TH = (const float*)d_in[1];   // theta fp32
    const float* W  = (const float*)d_in[2];   // W_combine fp32
    const float* BI = (const float*)d_in[3];   // b_combine fp32
    float* OUT = (float*)d_out;                // fp32

    f16* A  = (f16*)d_ws;                        // 16 MiB
    f16* Wb = (f16*)((char*)d_ws + (16u << 20)); // 512 KiB

    attn_stage<<<dim3(4096), dim3(256), 0, stream>>>(X, TH, W, Wb, A);
    gemm_bias<<<dim3(512), dim3(256), 0, stream>>>(A, Wb, BI, OUT);
}

// Round 15
// 110.273 us; speedup vs baseline: 1.0519x; 1.0519x over previous
//
#include <hip/hip_runtime.h>

typedef __attribute__((ext_vector_type(2))) float  f32x2;
typedef __attribute__((ext_vector_type(4))) float  f32x4;
typedef __attribute__((ext_vector_type(4))) unsigned int u32x4;
typedef _Float16 f16;
typedef __attribute__((ext_vector_type(2))) _Float16 f16x2;
typedef __attribute__((ext_vector_type(4))) _Float16 f16x4;
typedef __attribute__((ext_vector_type(8))) _Float16 f16x8;

#define S_LEN 2048
#define E_DIM 512
#define NH 64
#define DK 8

// ---------------------------------------------------------------------------
// Kernel 1: MFMA attention — EXACT R14 (best measured; attn+gap = 17.3us via
// R17 probe). Untouched this round.
// ---------------------------------------------------------------------------
__global__ __launch_bounds__(256) void attn_stage(
    const float* __restrict__ X,    // (8,2048,512) fp32
    const float* __restrict__ TH,   // (8,) fp32
    const float* __restrict__ W,    // (512,512) fp32
    f16* __restrict__ Wb,           // ws: 512x512 f16
    f16* __restrict__ A)            // ws: 16384 x 512 fp16
{
    __shared__ __align__(16) f16 Ps[4][NH][DK];   // 4 KB
    __shared__ __align__(16) f16 Pt[4][16][72];   // 9 KB
    __shared__ __align__(16) f16 Ev[4][NH * NH];  // 32 KB
    const int tid  = threadIdx.x;
    const int wv   = tid >> 6;
    const int lane = tid & 63;
    const int q    = lane >> 4;
    const int l    = lane & 15;
    const int t    = blockIdx.x * 4 + wv;    // token id

    // Side job: W fp32 -> f16 (65536 float4s == 256 blocks x 256 threads)
    if (blockIdx.x < 256) {
        const int i = blockIdx.x * 256 + tid;
        const float4 v = *(const float4*)(W + (size_t)i * 4);
        f16x4 o = {(f16)v.x, (f16)v.y, (f16)v.z, (f16)v.w};
        *(f16x4*)(Wb + (size_t)i * 4) = o;
    }

    const float4 t0 = *(const float4*)(TH);
    const float4 t1 = *(const float4*)(TH + 4);
    const float4 x0 = *(const float4*)(X + (size_t)t * E_DIM + lane * DK);
    const float4 x1 = *(const float4*)(X + (size_t)t * E_DIM + lane * DK + 4);

    float p[DK];
    p[0] = __cosf(x0.x + t0.x); p[1] = __cosf(x0.y + t0.y);
    p[2] = __cosf(x0.z + t0.z); p[3] = __cosf(x0.w + t0.w);
    p[4] = __cosf(x1.x + t1.x); p[5] = __cosf(x1.y + t1.y);
    p[6] = __cosf(x1.z + t1.z); p[7] = __cosf(x1.w + t1.w);

    // Ps[h][d] = p*cs  (cs^2 = (1/sqrt(8))*log2(e))
    const float cs = 0.714227053f;
    f16x8 psv;
    #pragma unroll
    for (int d = 0; d < DK; ++d) psv[d] = (f16)(p[d] * cs);
    *(f16x8*)&Ps[wv][lane][0] = psv;
    #pragma unroll
    for (int d = 0; d < DK; ++d) Pt[wv][d][lane] = (f16)p[d];
    __syncthreads();

    const f16x8 z8  = {(f16)0,(f16)0,(f16)0,(f16)0,(f16)0,(f16)0,(f16)0,(f16)0};
    const f16x8 one8= {(f16)1,(f16)1,(f16)1,(f16)1,(f16)1,(f16)1,(f16)1,(f16)1};

    f16x8 f[4];
    #pragma unroll
    for (int i = 0; i < 4; ++i) {
        const f16x8 v = *(const f16x8*)&Ps[wv][i*16 + l][0];
        f[i] = (q == 0) ? v : z8;
    }
    f32x4 St[4][4];
    #pragma unroll
    for (int i = 0; i < 4; ++i)
        #pragma unroll
        for (int jb = 0; jb < 4; ++jb) {
            f32x4 zc = {0.f, 0.f, 0.f, 0.f};
            St[i][jb] = __builtin_amdgcn_mfma_f32_16x16x32_f16(f[i], f[jb], zc, 0, 0, 0);
        }

    // E = exp2(S2), row-major via symmetry; chunk-8 XOR swizzle on cols.
    #pragma unroll
    for (int i = 0; i < 4; ++i)
        #pragma unroll
        for (int jb = 0; jb < 4; ++jb) {
            const float e0 = __builtin_amdgcn_exp2f(St[i][jb][0]);
            const float e1 = __builtin_amdgcn_exp2f(St[i][jb][1]);
            const float e2 = __builtin_amdgcn_exp2f(St[i][jb][2]);
            const float e3 = __builtin_amdgcn_exp2f(St[i][jb][3]);
            f16x4 w4;
            w4[0] = (f16)e0; w4[1] = (f16)e1; w4[2] = (f16)e2; w4[3] = (f16)e3;
            const int row = jb * 16 + l;
            const int c8  = (i * 2 + (q >> 1)) ^ (l & 7);
            const int col = c8 * 8 + (q & 1) * 4;
            *(f16x4*)&Ev[wv][row * 64 + col] = w4;
        }
    __syncthreads();

    // D2 = [Pᵀ; ones; 0]·Eᵀ over K=64.
    f32x4 d2[4] = {};
    #pragma unroll
    for (int kh = 0; kh < 2; ++kh) {
        const f16x8 av  = *(const f16x8*)&Pt[wv][l][kh * 32 + q * 8];
        const f16x8 a2f = (l < 8) ? av : ((l == 8) ? one8 : z8);
        #pragma unroll
        for (int nb = 0; nb < 4; ++nb) {
            const int c8 = (kh * 4 + q) ^ (l & 7);
            const f16x8 bv = *(const f16x8*)&Ev[wv][(nb * 16 + l) * 64 + c8 * 8];
            d2[nb] = __builtin_amdgcn_mfma_f32_16x16x32_f16(a2f, bv, d2[nb], 0, 0, 0);
        }
    }

    float rsinv[4];
    #pragma unroll
    for (int nb = 0; nb < 4; ++nb) {
        const int rs = __builtin_amdgcn_ds_bpermute((32 + l) * 4,
                           __float_as_int(d2[nb][0]));
        rsinv[nb] = __builtin_amdgcn_rcpf(__int_as_float(rs));
    }

    if (lane < 32) {
        const int s   = t & (S_LEN - 1);
        const int cb  = (t & 63) * DK + q * 4;
        const int rb  = ((t >> 11) << 11) + (s >> 6);
        #pragma unroll
        for (int nb = 0; nb < 4; ++nb) {
            const int h   = nb * 16 + l;
            const int row = rb + h * 32;
            f16x4 o;
            #pragma unroll
            for (int r = 0; r < 4; ++r) o[r] = (f16)(d2[nb][r] * rsinv[nb]);
            *(f16x4*)(A + (size_t)row * E_DIM + cb) = o;   // normal store (L2-merged)
        }
    }
}

// ---------------------------------------------------------------------------
// Kernel 2 (R20): OUT = A @ W^T + bias. R18 staged structure (validated 113.8)
// at HIGHER OCCUPANCY: GBM=64, BN=128, grid 1024 => 4 blocks/CU (16 waves/CU,
// was 8). Theory: R18's ~19.5us ~= SUM of phases (A-read + W-L2 + MFMA + OUT
// nt-write) because 2 lockstep blocks/CU can't overlap them; 4 blocks/CU lets
// one block's MFMA hide another's loads/stores. R19 (barrier-free, per-lane W
// gather) regressed: 16-line gathers amplified L2 transactions — reverted.
// W L2 traffic unchanged (1024 x 128KB = 128MB). XCD-aware bid mapping puts
// all 4 col-groups of an m-group on ONE XCD (bid&7) so A-tile is fetched to
// that L2 once (A HBM stays ~16MB). Perf-only assumption; correctness-safe.
// LDS: K-loop {ldsB 8KB, ldsA 4KB} unioned with epilogue ldsT 17KB -> 17KB.
// ---------------------------------------------------------------------------
#define GBM 64
#define GBK 32
#define GBN 128

__global__ __launch_bounds__(256, 4) void gemm_bias(
    const f16* __restrict__ A,        // 16384 x 512 f16 (ws)
    const f16* __restrict__ W,        // 512 x 512 f16 (ws)
    const float* __restrict__ BIAS,   // 512 fp32
    float* __restrict__ OUT)          // 16384 x 512 fp32
{
    // union: K-loop {ldsB 128x32 f16 = 8KB @0, ldsA 64x32 f16 = 4KB @8K}
    //        epilogue ldsT 4 waves x (16x68 f32 = 4352B) = 17408B
    __shared__ __align__(16) char ldsraw[4 * 16 * 68 * 4];
    f16* ldsB = (f16*)ldsraw;
    f16* ldsA = (f16*)(ldsraw + GBN * GBK * 2);
    const int tid  = threadIdx.x;
    const int lane = tid & 63;
    const int wave = tid >> 6;               // 0..3
    const int quad = lane >> 4;
    const int l16  = lane & 15;
    // XCD-aware mapping: all 4 col-groups of one m-group land on one XCD.
    const int xcd  = blockIdx.x & 7;
    const int k    = blockIdx.x >> 3;        // 0..127
    const int cg   = k & 3;                  // col-group 0..3
    const int mg   = xcd + 8 * (k >> 2);     // m-group 0..255
    const int m0   = mg * GBM;
    const int nb   = cg * GBN;               // block col base (= W row base)
    const int wm   = wave >> 1;              // 0..1: row half (32 rows)
    const int wnc  = (wave & 1) * 64;        // block-local col offset

    f32x4 acc[2][4] = {};

    for (int kb = 0; kb < 512; kb += GBK) {
        u32x4 wv8[2];
        int wr[2], wsx[2];
        #pragma unroll
        for (int i = 0; i < 2; ++i) {
            const int c  = tid + i * 256;     // 0..511
            const int r  = c >> 2;            // block-local W row 0..127
            const int cc = c & 3;             // 16B chunk in k-slice
            wr[i]  = r;
            wsx[i] = ((cc ^ (r & 3) ^ ((r >> 2) & 3))) * 8;
            wv8[i] = *(const u32x4*)(W + (size_t)(nb + r) * 512 + kb + cc * 8);
        }
        const int ar  = tid >> 2;             // A row 0..63
        const int acn = tid & 3;
        const int asx = ((acn ^ (ar & 3) ^ ((ar >> 2) & 3))) * 8;
        const u32x4 aval = *(const u32x4*)(A + (size_t)(m0 + ar) * 512 + kb + acn * 8);

        __syncthreads();   // previous iteration's readers done
        #pragma unroll
        for (int i = 0; i < 2; ++i)
            *(u32x4*)(ldsB + wr[i] * GBK + wsx[i]) = wv8[i];
        *(u32x4*)(ldsA + ar * GBK + asx) = aval;
        __syncthreads();   // staging visible

        f16x8 bfr[4];
        #pragma unroll
        for (int ni = 0; ni < 4; ++ni) {
            const int rw = wnc + ni * 16 + l16;              // 0..127
            const int sw = ((quad ^ (rw & 3) ^ ((rw >> 2) & 3))) * 8;
            bfr[ni] = *(const f16x8*)(ldsB + rw * GBK + sw);
        }
        #pragma unroll
        for (int mi = 0; mi < 2; ++mi) {
            const int ra = wm * 32 + mi * 16 + l16;          // 0..63
            const int sa = ((quad ^ (ra & 3) ^ ((ra >> 2) & 3))) * 8;
            const f16x8 afr = *(const f16x8*)(ldsA + ra * GBK + sa);
            #pragma unroll
            for (int ni = 0; ni < 4; ++ni)
                acc[mi][ni] = __builtin_amdgcn_mfma_f32_16x16x32_f16(
                    afr, bfr[ni], acc[mi][ni], 0, 0, 0);
        }
    }
    __syncthreads();       // K-loop LDS dead; safe to alias as ldsT

    // ---- epilogue: per-wave private transpose region (intra-wave DS order
    //      guarantees write->read; pattern validated in R19) ----
    float* ldsT = (float*)ldsraw + wave * (16 * 68);
    float4 bias4 = *(const float4*)(BIAS + nb + wnc + l16 * 4);
    #pragma unroll
    for (int mi = 0; mi < 2; ++mi) {
        #pragma unroll
        for (int ni = 0; ni < 4; ++ni)
            #pragma unroll
            for (int r = 0; r < 4; ++r)
                ldsT[(quad * 4 + r) * 68 + ni * 16 + l16] = acc[mi][ni][r];
        #pragma unroll
        for (int j = 0; j < 4; ++j) {
            const int row = j * 4 + quad;            // 0..15
            f32x4 v = *(const f32x4*)&ldsT[row * 68 + l16 * 4];
            v.x += bias4.x; v.y += bias4.y; v.z += bias4.z; v.w += bias4.w;
            float* o = OUT + (size_t)(m0 + wm * 32 + mi * 16 + row) * 512
                           + nb + wnc + l16 * 4;
            __builtin_nontemporal_store(v, (f32x4*)o);
        }
    }
}

extern "C" void kernel_launch(void* const* d_in, const int* in_sizes, int n_in,
                              void* d_out, int out_size, void* d_ws, size_t ws_size,
                              hipStream_t stream) {
    const float* X  = (const float*)d_in[0];   // x fp32
    const float* TH = (const float*)d_in[1];   // theta fp32
    const float* W  = (const float*)d_in[2];   // W_combine fp32
    const float* BI = (const float*)d_in[3];   // b_combine fp32
    float* OUT = (float*)d_out;                // fp32

    f16* A  = (f16*)d_ws;                        // 16 MiB
    f16* Wb = (f16*)((char*)d_ws + (16u << 20)); // 512 KiB

    attn_stage<<<dim3(4096), dim3(256), 0, stream>>>(X, TH, W, Wb, A);
    gemm_bias<<<dim3(1024), dim3(256), 0, stream>>>(A, Wb, BI, OUT);
}